// Round 14
// baseline (389.712 us; speedup 1.0000x reference)
//
#include <hip/hip_runtime.h>
#include <hip/hip_bf16.h>

#define NNODES 50000
#define MLP_HID 200
#define NB_SCAN 196   // ceil(NNODES/256)
#define CAP 128       // per-node edge cache (mean degree ~17)

// init kernel block ranges
#define NB_W1   256
#define NB_W2   256
#define NB_ZC   196
#define INIT_BLOCKS (NB_W1 + NB_W2 + NB_ZC + 1)

typedef __attribute__((ext_vector_type(8))) short bf16x8;
typedef __attribute__((ext_vector_type(4))) float f32x4;

__device__ __forceinline__ unsigned short f2bf(float x){
    unsigned u = __float_as_uint(x);
    unsigned r = (u + 0x7fffu + ((u >> 16) & 1u)) >> 16;
    return (unsigned short)r;
}
__device__ __forceinline__ float bflo(unsigned u){ return __uint_as_float(u << 16); }
__device__ __forceinline__ float bfhi(unsigned u){ return __uint_as_float(u & 0xffff0000u); }

// ---------------- init: W1T, W2T, zero cnt & bn accumulators -----------------
__global__ __launch_bounds__(256) void init_all(
    const float* __restrict__ W1, unsigned short* __restrict__ W1T,
    const float* __restrict__ W2, unsigned short* __restrict__ W2T,
    int* __restrict__ cnt, float* __restrict__ bn_acc /*400 floats*/)
{
    const int b = blockIdx.x, tid = threadIdx.x;
    if (b < NB_W1){
        int c = b;
        if (tid < 128) W1T[(size_t)c * 128 + tid] = f2bf(W1[(size_t)tid * 256 + c]);
    } else if (b < NB_W1 + NB_W2){
        int c = b - NB_W1;
        if (tid < 64) W2T[(size_t)c * 64 + tid] = f2bf(W2[(size_t)tid * 256 + c]);
    } else if (b < NB_W1 + NB_W2 + NB_ZC){
        int i = (b - NB_W1 - NB_W2) * 256 + tid;
        if (i < NNODES) cnt[i] = 0;
    } else {
        if (tid < 2 * MLP_HID - 256) bn_acc[256 + tid] = 0.f;
        bn_acc[tid] = 0.f;
    }
}

// ---------------- MFMA GEMM + attn-dot epilogue ------------------------------
// F32IN: A is f32 (bf16-rounded in-register). STOREH: write h table.
template<int K, bool F32IN, bool STOREH>
__global__ __launch_bounds__(256) void mfma_gemm_attn(
    const void* __restrict__ Aptr,
    const unsigned short* __restrict__ WT,
    const float* __restrict__ al, const float* __restrict__ ar,
    unsigned short* __restrict__ hb,
    float* __restrict__ el, float* __restrict__ er, int M)
{
    const int wv = threadIdx.x >> 6, lane = threadIdx.x & 63;
    const int r0 = blockIdx.x * 64 + wv * 16;
    const int l15 = lane & 15, ks = lane >> 4;

    f32x4 acc[16];
    #pragma unroll
    for (int nt = 0; nt < 16; nt++)
        #pragma unroll
        for (int q = 0; q < 4; q++) acc[nt][q] = 0.f;

    const int arow = min(r0 + l15, M - 1);
    const unsigned short* aptr_b = (const unsigned short*)Aptr + (size_t)arow * K + ks * 8;
    const float*          aptr_f = (const float*)Aptr          + (size_t)arow * K + ks * 8;
    const unsigned short* bptr = WT + (size_t)l15 * K + ks * 8;

    #pragma unroll
    for (int k0 = 0; k0 < K; k0 += 32){
        bf16x8 a;
        if (F32IN){
            float4 f0 = *(const float4*)(aptr_f + k0);
            float4 f1 = *(const float4*)(aptr_f + k0 + 4);
            a[0] = (short)f2bf(f0.x); a[1] = (short)f2bf(f0.y);
            a[2] = (short)f2bf(f0.z); a[3] = (short)f2bf(f0.w);
            a[4] = (short)f2bf(f1.x); a[5] = (short)f2bf(f1.y);
            a[6] = (short)f2bf(f1.z); a[7] = (short)f2bf(f1.w);
        } else {
            a = *(const bf16x8*)(aptr_b + k0);
        }
        #pragma unroll
        for (int nt = 0; nt < 16; nt++){
            bf16x8 b = *(const bf16x8*)(bptr + (size_t)nt * 16 * K + k0);
            acc[nt] = __builtin_amdgcn_mfma_f32_16x16x32_bf16(a, b, acc[nt], 0, 0, 0);
        }
    }

    float elv[4][4], erv[4][4];
    #pragma unroll
    for (int r = 0; r < 4; r++)
        #pragma unroll
        for (int hh = 0; hh < 4; hh++){ elv[r][hh] = 0.f; erv[r][hh] = 0.f; }

    #pragma unroll
    for (int nt = 0; nt < 16; nt++){
        int col = nt * 16 + l15;
        float alv = al[col], arv = ar[col];
        #pragma unroll
        for (int reg = 0; reg < 4; reg++){
            elv[reg][nt >> 2] = fmaf(acc[nt][reg], alv, elv[reg][nt >> 2]);
            erv[reg][nt >> 2] = fmaf(acc[nt][reg], arv, erv[reg][nt >> 2]);
        }
    }
    #pragma unroll
    for (int o = 8; o > 0; o >>= 1){
        #pragma unroll
        for (int reg = 0; reg < 4; reg++)
            #pragma unroll
            for (int hh = 0; hh < 4; hh++){
                elv[reg][hh] += __shfl_xor(elv[reg][hh], o);
                erv[reg][hh] += __shfl_xor(erv[reg][hh], o);
            }
    }
    if (l15 == 0){
        #pragma unroll
        for (int reg = 0; reg < 4; reg++){
            int r = r0 + ks * 4 + reg;
            if (r < M){
                #pragma unroll
                for (int hh = 0; hh < 4; hh++){
                    el[r * 4 + hh] = elv[reg][hh];
                    er[r * 4 + hh] = erv[reg][hh];
                }
            }
        }
    }

    if constexpr (STOREH){
        __shared__ __align__(16) unsigned short hbuf[4][16][264];
        #pragma unroll
        for (int nt = 0; nt < 16; nt++)
            #pragma unroll
            for (int reg = 0; reg < 4; reg++)
                hbuf[wv][ks * 4 + reg][nt * 16 + l15] = f2bf(acc[nt][reg]);
        #pragma unroll
        for (int t = 0; t < 8; t++){
            int chunk = t * 64 + lane;
            int rr = chunk >> 5;
            int cc = (chunk & 31) * 8;
            int r = r0 + rr;
            if (r < M){
                uint4 v = *(const uint4*)&hbuf[wv][rr][cc];
                *(uint4*)&hb[(size_t)r * 256 + cc] = v;
            }
        }
    }
}

// ---------------- apply W2 to aggregate + epilogue (layer 2 tail) ------------
// o2[n][d] = mean_h relu( agg2[n][h*64:] @ W2T[h*64+d] + b2[h*64+d] )
__global__ __launch_bounds__(256) void mfma_apply_w2(
    const unsigned short* __restrict__ agg2,   // [N][256] bf16 ([n][h*64+k])
    const unsigned short* __restrict__ W2T,    // [256][64]
    const float* __restrict__ b2,
    float* __restrict__ out_f, int M)
{
    const int wv = threadIdx.x >> 6, lane = threadIdx.x & 63;
    const int r0 = blockIdx.x * 64 + wv * 16;
    const int l15 = lane & 15, ks = lane >> 4;
    const int arow = min(r0 + l15, M - 1);

    f32x4 acc[4][4];   // [head][col-tile]
    #pragma unroll
    for (int h = 0; h < 4; h++)
        #pragma unroll
        for (int nt = 0; nt < 4; nt++)
            #pragma unroll
            for (int q = 0; q < 4; q++) acc[h][nt][q] = 0.f;

    #pragma unroll
    for (int k0 = 0; k0 < 64; k0 += 32){
        #pragma unroll
        for (int h = 0; h < 4; h++){
            bf16x8 a = *(const bf16x8*)&agg2[(size_t)arow * 256 + h * 64 + ks * 8 + k0];
            #pragma unroll
            for (int nt = 0; nt < 4; nt++){
                bf16x8 b = *(const bf16x8*)&W2T[(size_t)(h * 64 + nt * 16 + l15) * 64 + ks * 8 + k0];
                acc[h][nt] = __builtin_amdgcn_mfma_f32_16x16x32_bf16(a, b, acc[h][nt], 0, 0, 0);
            }
        }
    }

    // epilogue: relu(+b2) per head, mean over heads; repack via LDS
    __shared__ __align__(16) float obuf[4][16][68];
    #pragma unroll
    for (int nt = 0; nt < 4; nt++){
        #pragma unroll
        for (int reg = 0; reg < 4; reg++){
            float s = 0.f;
            #pragma unroll
            for (int h = 0; h < 4; h++)
                s += fmaxf(acc[h][nt][reg] + b2[h * 64 + nt * 16 + l15], 0.f);
            obuf[wv][ks * 4 + reg][nt * 16 + l15] = s * 0.25f;
        }
    }
    #pragma unroll
    for (int t = 0; t < 4; t++){
        int chunk = t * 64 + lane;       // 0..255
        int rr = chunk >> 4;             // 0..15
        int cc = (chunk & 15) * 4;       // 0..60
        int r = r0 + rr;
        if (r < M){
            float4 v = *(const float4*)&obuf[wv][rr][cc];
            *(float4*)&out_f[(size_t)r * 64 + cc] = v;
        }
    }
}

// ---------------- f32 GEMM (MLP layer): +bias +relu, fused BN partials -------
template<int KT, bool RELU, bool BN>
__global__ __launch_bounds__(256) void gemm_tile(const float* __restrict__ A,
                                                 const float* __restrict__ B,
                                                 const float* __restrict__ bias,
                                                 float* __restrict__ C,
                                                 float* __restrict__ bn_sum,
                                                 float* __restrict__ bn_sumsq,
                                                 int M, int Nc){
    __shared__ float As[16][64];
    __shared__ float Bs[16][64];
    __shared__ float bnred[16][64];
    const int tid = threadIdx.x;
    const int tx = tid & 15, ty = tid >> 4;
    const int r0 = blockIdx.y * 64, c0 = blockIdx.x * 64;
    float acc[4][4] = {};
    const int lr  = tid >> 2,  lk4 = (tid & 3) * 4;
    const int bk  = tid >> 4,  bc4 = (tid & 15) * 4;

    for (int k0 = 0; k0 < KT; k0 += 16){
        float4 av = make_float4(0.f,0.f,0.f,0.f);
        if (r0 + lr < M) av = *(const float4*)&A[(size_t)(r0 + lr) * KT + k0 + lk4];
        As[lk4+0][lr] = av.x; As[lk4+1][lr] = av.y;
        As[lk4+2][lr] = av.z; As[lk4+3][lr] = av.w;

        if (c0 + bc4 + 3 < Nc){
            float4 bv = *(const float4*)&B[(size_t)(k0 + bk) * Nc + c0 + bc4];
            Bs[bk][bc4+0] = bv.x; Bs[bk][bc4+1] = bv.y;
            Bs[bk][bc4+2] = bv.z; Bs[bk][bc4+3] = bv.w;
        } else {
            #pragma unroll
            for (int j = 0; j < 4; j++){
                int c = c0 + bc4 + j;
                Bs[bk][bc4+j] = (c < Nc) ? B[(size_t)(k0 + bk) * Nc + c] : 0.f;
            }
        }
        __syncthreads();
        #pragma unroll
        for (int kk = 0; kk < 16; kk++){
            float4 a = *(const float4*)&As[kk][ty*4];
            float4 b = *(const float4*)&Bs[kk][tx*4];
            float arr[4] = {a.x,a.y,a.z,a.w};
            float brr[4] = {b.x,b.y,b.z,b.w};
            #pragma unroll
            for (int i = 0; i < 4; i++)
                #pragma unroll
                for (int j = 0; j < 4; j++)
                    acc[i][j] = fmaf(arr[i], brr[j], acc[i][j]);
        }
        __syncthreads();
    }

    float cs[4] = {0,0,0,0}, css[4] = {0,0,0,0};
    #pragma unroll
    for (int i = 0; i < 4; i++){
        int r = r0 + ty*4 + i;
        bool rok = r < M;
        #pragma unroll
        for (int j = 0; j < 4; j++){
            int c = c0 + tx*4 + j;
            if (c >= Nc) continue;
            float v = acc[i][j];
            if (bias) v += bias[c];
            if (RELU) v = fmaxf(v, 0.f);
            if (rok){
                C[(size_t)r * Nc + c] = v;
                if (BN){ cs[j] += v; css[j] += v * v; }
            }
        }
    }
    if (BN){
        #pragma unroll
        for (int j = 0; j < 4; j++) bnred[ty][tx*4+j] = cs[j];
        __syncthreads();
        if (tid < 64){
            float s = 0.f;
            #pragma unroll
            for (int t = 0; t < 16; t++) s += bnred[t][tid];
            if (c0 + tid < Nc) atomicAdd(&bn_sum[c0 + tid], s);
        }
        __syncthreads();
        #pragma unroll
        for (int j = 0; j < 4; j++) bnred[ty][tx*4+j] = css[j];
        __syncthreads();
        if (tid < 64){
            float s = 0.f;
            #pragma unroll
            for (int t = 0; t < 16; t++) s += bnred[t][tid];
            if (c0 + tid < Nc) atomicAdd(&bn_sumsq[c0 + tid], s);
        }
    }
}

// ---------------- CSR build (hierarchical scan) ----------------
__global__ __launch_bounds__(256) void csr_count(const int* __restrict__ dst,
                                                 int* __restrict__ cnt, int E){
    int e = blockIdx.x * blockDim.x + threadIdx.x;
    if (e < E) atomicAdd(&cnt[dst[e]], 1);
}

__global__ __launch_bounds__(256) void csr_bsum(const int* __restrict__ cnt,
                                                int* __restrict__ bsum){
    __shared__ int red[256];
    int i = blockIdx.x * 256 + threadIdx.x;
    red[threadIdx.x] = (i < NNODES) ? cnt[i] : 0;
    __syncthreads();
    for (int off = 128; off > 0; off >>= 1){
        if (threadIdx.x < off) red[threadIdx.x] += red[threadIdx.x + off];
        __syncthreads();
    }
    if (threadIdx.x == 0) bsum[blockIdx.x] = red[0];
}

__global__ __launch_bounds__(256) void csr_bscan(const int* __restrict__ bsum,
                                                 int* __restrict__ boff){
    __shared__ int part[256];
    int t = threadIdx.x;
    int v = (t < NB_SCAN) ? bsum[t] : 0;
    part[t] = v;
    __syncthreads();
    for (int off = 1; off < 256; off <<= 1){
        int u = (t >= off) ? part[t - off] : 0;
        __syncthreads();
        part[t] += u;
        __syncthreads();
    }
    if (t < NB_SCAN) boff[t] = part[t] - v;
}

__global__ __launch_bounds__(256) void csr_fill(const int* __restrict__ cnt,
                                                const int* __restrict__ boff,
                                                int* __restrict__ row_ptr,
                                                int* __restrict__ cursor){
    __shared__ int part[256];
    int b = blockIdx.x, t = threadIdx.x;
    int i = b * 256 + t;
    int c = (i < NNODES) ? cnt[i] : 0;
    part[t] = c;
    __syncthreads();
    for (int off = 1; off < 256; off <<= 1){
        int u = (t >= off) ? part[t - off] : 0;
        __syncthreads();
        part[t] += u;
        __syncthreads();
    }
    int excl = part[t] - c + boff[b];
    if (i < NNODES){ row_ptr[i] = excl; cursor[i] = excl; }
    if (i == NNODES - 1) row_ptr[NNODES] = excl + c;
}

__global__ __launch_bounds__(256) void csr_scatter(const int* __restrict__ src,
                                                   const int* __restrict__ dst,
                                                   int* __restrict__ cursor,
                                                   int* __restrict__ col_src, int E){
    int e = blockIdx.x * blockDim.x + threadIdx.x;
    if (e >= E) return;
    int pos = atomicAdd(&cursor[dst[e]], 1);
    col_src[pos] = src[e];
}

// ---------------- edge kernel v7 (layer 1): wave/node, gather h rows ---------
__global__ __launch_bounds__(256) void gat_edge_v7(
    const int* __restrict__ row_ptr, const int* __restrict__ col_src,
    const float* __restrict__ el, const float* __restrict__ er,
    const unsigned short* __restrict__ hb, const float* __restrict__ bias,
    unsigned short* __restrict__ out_b, int N)
{
    __shared__ float s_w[4][4][132];
    __shared__ int   s_idx[4][CAP];

    const int wv = threadIdx.x >> 6;
    const int lane = threadIdx.x & 63;
    const int n = blockIdx.x * 4 + wv;
    if (n >= N) return;

    const int rs = row_ptr[n], re = row_ptr[n + 1];
    const int K = re - rs;
    const float4 ern = *(const float4*)&er[n * 4];
    float (*sw)[132] = s_w[wv];
    int* sidx = s_idx[wv];

    float ls0 = 0.f, ls1 = 0.f, ls2 = 0.f, ls3 = 0.f;
    for (int k = lane; k < K; k += 64){
        int s = col_src[rs + k];
        float4 e4 = *(const float4*)&el[s * 4];
        float e0 = e4.x + ern.x; e0 = (e0 >= 0.f) ? e0 : 0.2f * e0;
        float e1 = e4.y + ern.y; e1 = (e1 >= 0.f) ? e1 : 0.2f * e1;
        float e2 = e4.z + ern.z; e2 = (e2 >= 0.f) ? e2 : 0.2f * e2;
        float e3 = e4.w + ern.w; e3 = (e3 >= 0.f) ? e3 : 0.2f * e3;
        float w0 = __expf(e0), w1 = __expf(e1), w2 = __expf(e2), w3 = __expf(e3);
        if (k < CAP){
            sidx[k] = s;
            sw[0][k] = w0; sw[1][k] = w1; sw[2][k] = w2; sw[3][k] = w3;
        }
        ls0 += w0; ls1 += w1; ls2 += w2; ls3 += w3;
    }
    #pragma unroll
    for (int o = 32; o > 0; o >>= 1){
        ls0 += __shfl_xor(ls0, o); ls1 += __shfl_xor(ls1, o);
        ls2 += __shfl_xor(ls2, o); ls3 += __shfl_xor(ls3, o);
    }
    const int slot = lane >> 5;
    const int c8   = (lane & 31) * 8;
    const int hc   = c8 >> 6;
    const float invh = 1.f / (hc == 0 ? ls0 : hc == 1 ? ls1 : hc == 2 ? ls2 : ls3);

    float acc[8];
    #pragma unroll
    for (int q = 0; q < 8; q++) acc[q] = 0.f;

    for (int base = 0; base < K; base += CAP){
        if (base > 0){
            for (int k = base + lane; k < min(K, base + CAP); k += 64){
                int s = col_src[rs + k];
                float4 e4 = *(const float4*)&el[s * 4];
                float e0 = e4.x + ern.x; e0 = (e0 >= 0.f) ? e0 : 0.2f * e0;
                float e1 = e4.y + ern.y; e1 = (e1 >= 0.f) ? e1 : 0.2f * e1;
                float e2 = e4.z + ern.z; e2 = (e2 >= 0.f) ? e2 : 0.2f * e2;
                float e3 = e4.w + ern.w; e3 = (e3 >= 0.f) ? e3 : 0.2f * e3;
                int kk = k - base;
                sidx[kk] = s;
                sw[0][kk] = __expf(e0); sw[1][kk] = __expf(e1);
                sw[2][kk] = __expf(e2); sw[3][kk] = __expf(e3);
            }
        }
        const int rem = min(CAP, K - base);
        for (int j = slot; j < rem; j += 8){
            int   j1 = j + 2, j2 = j + 4, j3 = j + 6;
            int   jc1 = min(j1, rem - 1), jc2 = min(j2, rem - 1), jc3 = min(j3, rem - 1);
            float w0v = sw[hc][j];
            float w1v = (j1 < rem) ? sw[hc][j1] : 0.f;
            float w2v = (j2 < rem) ? sw[hc][j2] : 0.f;
            float w3v = (j3 < rem) ? sw[hc][j3] : 0.f;
            int   s0 = sidx[j], s1 = sidx[jc1], s2 = sidx[jc2], s3 = sidx[jc3];
            uint4 v0 = *(const uint4*)&hb[(size_t)s0 * 256 + c8];
            uint4 v1 = *(const uint4*)&hb[(size_t)s1 * 256 + c8];
            uint4 v2 = *(const uint4*)&hb[(size_t)s2 * 256 + c8];
            uint4 v3 = *(const uint4*)&hb[(size_t)s3 * 256 + c8];
            acc[0] = fmaf(w0v, bflo(v0.x), acc[0]); acc[1] = fmaf(w0v, bfhi(v0.x), acc[1]);
            acc[2] = fmaf(w0v, bflo(v0.y), acc[2]); acc[3] = fmaf(w0v, bfhi(v0.y), acc[3]);
            acc[4] = fmaf(w0v, bflo(v0.z), acc[4]); acc[5] = fmaf(w0v, bfhi(v0.z), acc[5]);
            acc[6] = fmaf(w0v, bflo(v0.w), acc[6]); acc[7] = fmaf(w0v, bfhi(v0.w), acc[7]);
            acc[0] = fmaf(w1v, bflo(v1.x), acc[0]); acc[1] = fmaf(w1v, bfhi(v1.x), acc[1]);
            acc[2] = fmaf(w1v, bflo(v1.y), acc[2]); acc[3] = fmaf(w1v, bfhi(v1.y), acc[3]);
            acc[4] = fmaf(w1v, bflo(v1.z), acc[4]); acc[5] = fmaf(w1v, bfhi(v1.z), acc[5]);
            acc[6] = fmaf(w1v, bflo(v1.w), acc[6]); acc[7] = fmaf(w1v, bfhi(v1.w), acc[7]);
            acc[0] = fmaf(w2v, bflo(v2.x), acc[0]); acc[1] = fmaf(w2v, bfhi(v2.x), acc[1]);
            acc[2] = fmaf(w2v, bflo(v2.y), acc[2]); acc[3] = fmaf(w2v, bfhi(v2.y), acc[3]);
            acc[4] = fmaf(w2v, bflo(v2.z), acc[4]); acc[5] = fmaf(w2v, bfhi(v2.z), acc[5]);
            acc[6] = fmaf(w2v, bflo(v2.w), acc[6]); acc[7] = fmaf(w2v, bfhi(v2.w), acc[7]);
            acc[0] = fmaf(w3v, bflo(v3.x), acc[0]); acc[1] = fmaf(w3v, bfhi(v3.x), acc[1]);
            acc[2] = fmaf(w3v, bflo(v3.y), acc[2]); acc[3] = fmaf(w3v, bfhi(v3.y), acc[3]);
            acc[4] = fmaf(w3v, bflo(v3.z), acc[4]); acc[5] = fmaf(w3v, bfhi(v3.z), acc[5]);
            acc[6] = fmaf(w3v, bflo(v3.w), acc[6]); acc[7] = fmaf(w3v, bfhi(v3.w), acc[7]);
        }
    }

    #pragma unroll
    for (int q = 0; q < 8; q++){
        acc[q] *= invh;
        acc[q] += __shfl_xor(acc[q], 32);
        acc[q] = fmaxf(acc[q] + bias[c8 + q], 0.f);
        acc[q] += __shfl_xor(acc[q], 8);
        acc[q] += __shfl_xor(acc[q], 16);
        acc[q] *= 0.25f;
    }
    if (lane < 8){
        uint4 pb;
        pb.x = (unsigned)f2bf(acc[0]) | ((unsigned)f2bf(acc[1]) << 16);
        pb.y = (unsigned)f2bf(acc[2]) | ((unsigned)f2bf(acc[3]) << 16);
        pb.z = (unsigned)f2bf(acc[4]) | ((unsigned)f2bf(acc[5]) << 16);
        pb.w = (unsigned)f2bf(acc[6]) | ((unsigned)f2bf(acc[7]) << 16);
        *(uint4*)&out_b[(size_t)n * 64 + lane * 8] = pb;
    }
}

// ---------------- edge kernel (layer 2): aggregate in o1-space ---------------
// agg2[n][h*64+d] = (1/S_h) * sum_k w_k^{(h)} * o1[s_k][d]  — gather 128B rows.
// 64 lanes = 8 slots (bits 3-5) x 8 chunks (bits 0-2); 4 head-accs per lane.
// 4-deep clamped gather unroll (j, j+8, j+16, j+24) for load ILP.
#define AGG_EDGE(W0,W1,W2,W3,V) \
    acc[0][0]=fmaf(W0,bflo(V.x),acc[0][0]); acc[0][1]=fmaf(W0,bfhi(V.x),acc[0][1]); \
    acc[0][2]=fmaf(W0,bflo(V.y),acc[0][2]); acc[0][3]=fmaf(W0,bfhi(V.y),acc[0][3]); \
    acc[0][4]=fmaf(W0,bflo(V.z),acc[0][4]); acc[0][5]=fmaf(W0,bfhi(V.z),acc[0][5]); \
    acc[0][6]=fmaf(W0,bflo(V.w),acc[0][6]); acc[0][7]=fmaf(W0,bfhi(V.w),acc[0][7]); \
    acc[1][0]=fmaf(W1,bflo(V.x),acc[1][0]); acc[1][1]=fmaf(W1,bfhi(V.x),acc[1][1]); \
    acc[1][2]=fmaf(W1,bflo(V.y),acc[1][2]); acc[1][3]=fmaf(W1,bfhi(V.y),acc[1][3]); \
    acc[1][4]=fmaf(W1,bflo(V.z),acc[1][4]); acc[1][5]=fmaf(W1,bfhi(V.z),acc[1][5]); \
    acc[1][6]=fmaf(W1,bflo(V.w),acc[1][6]); acc[1][7]=fmaf(W1,bfhi(V.w),acc[1][7]); \
    acc[2][0]=fmaf(W2,bflo(V.x),acc[2][0]); acc[2][1]=fmaf(W2,bfhi(V.x),acc[2][1]); \
    acc[2][2]=fmaf(W2,bflo(V.y),acc[2][2]); acc[2][3]=fmaf(W2,bfhi(V.y),acc[2][3]); \
    acc[2][4]=fmaf(W2,bflo(V.z),acc[2][4]); acc[2][5]=fmaf(W2,bfhi(V.z),acc[2][5]); \
    acc[2][6]=fmaf(W2,bflo(V.w),acc[2][6]); acc[2][7]=fmaf(W2,bfhi(V.w),acc[2][7]); \
    acc[3][0]=fmaf(W3,bflo(V.x),acc[3][0]); acc[3][1]=fmaf(W3,bfhi(V.x),acc[3][1]); \
    acc[3][2]=fmaf(W3,bflo(V.y),acc[3][2]); acc[3][3]=fmaf(W3,bfhi(V.y),acc[3][3]); \
    acc[3][4]=fmaf(W3,bflo(V.z),acc[3][4]); acc[3][5]=fmaf(W3,bfhi(V.z),acc[3][5]); \
    acc[3][6]=fmaf(W3,bflo(V.w),acc[3][6]); acc[3][7]=fmaf(W3,bfhi(V.w),acc[3][7]);

__global__ __launch_bounds__(256) void gat_edge_agg(
    const int* __restrict__ row_ptr, const int* __restrict__ col_src,
    const float* __restrict__ el, const float* __restrict__ er,
    const unsigned short* __restrict__ o1, unsigned short* __restrict__ agg2, int N)
{
    __shared__ float s_w[4][4][132];
    __shared__ int   s_idx[4][CAP];

    const int wv = threadIdx.x >> 6;
    const int lane = threadIdx.x & 63;
    const int n = blockIdx.x * 4 + wv;
    if (n >= N) return;

    const int rs = row_ptr[n], re = row_ptr[n + 1];
    const int K = re - rs;
    const float4 ern = *(const float4*)&er[n * 4];
    float (*sw)[132] = s_w[wv];
    int* sidx = s_idx[wv];

    // phase 1: weights (identical to v7)
    float ls0 = 0.f, ls1 = 0.f, ls2 = 0.f, ls3 = 0.f;
    for (int k = lane; k < K; k += 64){
        int s = col_src[rs + k];
        float4 e4 = *(const float4*)&el[s * 4];
        float e0 = e4.x + ern.x; e0 = (e0 >= 0.f) ? e0 : 0.2f * e0;
        float e1 = e4.y + ern.y; e1 = (e1 >= 0.f) ? e1 : 0.2f * e1;
        float e2 = e4.z + ern.z; e2 = (e2 >= 0.f) ? e2 : 0.2f * e2;
        float e3 = e4.w + ern.w; e3 = (e3 >= 0.f) ? e3 : 0.2f * e3;
        float w0 = __expf(e0), w1 = __expf(e1), w2 = __expf(e2), w3 = __expf(e3);
        if (k < CAP){
            sidx[k] = s;
            sw[0][k] = w0; sw[1][k] = w1; sw[2][k] = w2; sw[3][k] = w3;
        }
        ls0 += w0; ls1 += w1; ls2 += w2; ls3 += w3;
    }
    #pragma unroll
    for (int o = 32; o > 0; o >>= 1){
        ls0 += __shfl_xor(ls0, o); ls1 += __shfl_xor(ls1, o);
        ls2 += __shfl_xor(ls2, o); ls3 += __shfl_xor(ls3, o);
    }

    const int slot = lane >> 3;          // 0..7
    const int c8   = (lane & 7) * 8;     // dim chunk within 64
    float acc[4][8];
    #pragma unroll
    for (int h = 0; h < 4; h++)
        #pragma unroll
        for (int q = 0; q < 8; q++) acc[h][q] = 0.f;

    // phase 2: gather o1 rows (128B), 4 edges in flight per lane
    for (int base = 0; base < K; base += CAP){
        if (base > 0){
            for (int k = base + lane; k < min(K, base + CAP); k += 64){
                int s = col_src[rs + k];
                float4 e4 = *(const float4*)&el[s * 4];
                float e0 = e4.x + ern.x; e0 = (e0 >= 0.f) ? e0 : 0.2f * e0;
                float e1 = e4.y + ern.y; e1 = (e1 >= 0.f) ? e1 : 0.2f * e1;
                float e2 = e4.z + ern.z; e2 = (e2 >= 0.f) ? e2 : 0.2f * e2;
                float e3 = e4.w + ern.w; e3 = (e3 >= 0.f) ? e3 : 0.2f * e3;
                int kk = k - base;
                sidx[kk] = s;
                sw[0][kk] = __expf(e0); sw[1][kk] = __expf(e1);
                sw[2][kk] = __expf(e2); sw[3][kk] = __expf(e3);
            }
        }
        const int rem = min(CAP, K - base);
        for (int j = slot; j < rem; j += 32){
            int jA = j + 8, jB = j + 16, jC = j + 24;
            int cA = min(jA, rem - 1), cB = min(jB, rem - 1), cC = min(jC, rem - 1);
            int s0 = sidx[j], s1 = sidx[cA], s2 = sidx[cB], s3 = sidx[cC];
            uint4 v0 = *(const uint4*)&o1[(size_t)s0 * 64 + c8];
            uint4 v1 = *(const uint4*)&o1[(size_t)s1 * 64 + c8];
            uint4 v2 = *(const uint4*)&o1[(size_t)s2 * 64 + c8];
            uint4 v3 = *(const uint4*)&o1[(size_t)s3 * 64 + c8];
            {
                float w0 = sw[0][j], w1 = sw[1][j], w2 = sw[2][j], w3 = sw[3][j];
                AGG_EDGE(w0, w1, w2, w3, v0)
            }
            {
                float w0 = (jA < rem) ? sw[0][jA] : 0.f;
                float w1 = (jA < rem) ? sw[1][jA] : 0.f;
                float w2 = (jA < rem) ? sw[2][jA] : 0.f;
                float w3 = (jA < rem) ? sw[3][jA] : 0.f;
                AGG_EDGE(w0, w1, w2, w3, v1)
            }
            {
                float w0 = (jB < rem) ? sw[0][jB] : 0.f;
                float w1 = (jB < rem) ? sw[1][jB] : 0.f;
                float w2 = (jB < rem) ? sw[2][jB] : 0.f;
                float w3 = (jB < rem) ? sw[3][jB] : 0.f;
                AGG_EDGE(w0, w1, w2, w3, v2)
            }
            {
                float w0 = (jC < rem) ? sw[0][jC] : 0.f;
                float w1 = (jC < rem) ? sw[1][jC] : 0.f;
                float w2 = (jC < rem) ? sw[2][jC] : 0.f;
                float w3 = (jC < rem) ? sw[3][jC] : 0.f;
                AGG_EDGE(w0, w1, w2, w3, v3)
            }
        }
    }

    // reduce across 8 slots (lane bits 3..5)
    #pragma unroll
    for (int h = 0; h < 4; h++)
        #pragma unroll
        for (int q = 0; q < 8; q++){
            acc[h][q] += __shfl_xor(acc[h][q], 8);
            acc[h][q] += __shfl_xor(acc[h][q], 16);
            acc[h][q] += __shfl_xor(acc[h][q], 32);
        }

    if (lane < 8){
        const float inv[4] = {1.f / ls0, 1.f / ls1, 1.f / ls2, 1.f / ls3};
        #pragma unroll
        for (int h = 0; h < 4; h++){
            uint4 pb;
            pb.x = (unsigned)f2bf(acc[h][0] * inv[h]) | ((unsigned)f2bf(acc[h][1] * inv[h]) << 16);
            pb.y = (unsigned)f2bf(acc[h][2] * inv[h]) | ((unsigned)f2bf(acc[h][3] * inv[h]) << 16);
            pb.z = (unsigned)f2bf(acc[h][4] * inv[h]) | ((unsigned)f2bf(acc[h][5] * inv[h]) << 16);
            pb.w = (unsigned)f2bf(acc[h][6] * inv[h]) | ((unsigned)f2bf(acc[h][7] * inv[h]) << 16);
            *(uint4*)&agg2[(size_t)n * 256 + h * 64 + c8] = pb;
        }
    }
}

// ---------------- final linear (BN scale/shift computed inline) --------------
__global__ __launch_bounds__(256) void mlp2(const float* __restrict__ z,
                                            const float* __restrict__ bn_sum,
                                            const float* __restrict__ bn_sumsq,
                                            const float* __restrict__ gamma,
                                            const float* __restrict__ beta,
                                            const float* __restrict__ Wm2,
                                            const float* __restrict__ bm2,
                                            float* __restrict__ out,
                                            int Nrows){
    __shared__ float s_scale[MLP_HID], s_shift[MLP_HID];
    const int tid = threadIdx.x;
    if (tid < MLP_HID){
        float inv = 1.f / (float)Nrows;
        float mu = bn_sum[tid] * inv;
        float var = bn_sumsq[tid] * inv - mu * mu;
        float rstd = rsqrtf(var + 1e-5f);
        float sc = rstd * gamma[tid];
        s_scale[tid] = sc;
        s_shift[tid] = beta[tid] - mu * sc;
    }
    __syncthreads();
    int n = (blockIdx.x * 256 + tid) >> 6;
    if (n >= Nrows) return;
    int lane = tid & 63;
    float a0 = 0.f, a1 = 0.f;
    for (int k = lane; k < MLP_HID; k += 64){
        float zn = z[(size_t)n * MLP_HID + k] * s_scale[k] + s_shift[k];
        a0 = fmaf(zn, Wm2[k * 2 + 0], a0);
        a1 = fmaf(zn, Wm2[k * 2 + 1], a1);
    }
    #pragma unroll
    for (int o = 32; o > 0; o >>= 1){
        a0 += __shfl_xor(a0, o);
        a1 += __shfl_xor(a1, o);
    }
    if (lane == 0){
        out[n * 2 + 0] = a0 + bm2[0];
        out[n * 2 + 1] = a1 + bm2[1];
    }
}

extern "C" void kernel_launch(void* const* d_in, const int* in_sizes, int n_in,
                              void* d_out, int out_size, void* d_ws, size_t ws_size,
                              hipStream_t stream) {
    const float* feat  = (const float*)d_in[0];
    const int*   src   = (const int*)  d_in[1];
    const int*   dst   = (const int*)  d_in[2];
    const float* W1    = (const float*)d_in[3];
    const float* al1   = (const float*)d_in[4];
    const float* ar1   = (const float*)d_in[5];
    const float* b1    = (const float*)d_in[6];
    const float* W2    = (const float*)d_in[7];
    const float* al2   = (const float*)d_in[8];
    const float* ar2   = (const float*)d_in[9];
    const float* b2    = (const float*)d_in[10];
    const float* Wm1   = (const float*)d_in[11];
    const float* bm1   = (const float*)d_in[12];
    const float* gamma = (const float*)d_in[13];
    const float* beta  = (const float*)d_in[14];
    const float* Wm2   = (const float*)d_in[15];
    const float* bm2   = (const float*)d_in[16];
    const int E = in_sizes[1];
    float* out = (float*)d_out;

    // ---- workspace layout ----
    unsigned short* h_bf   = (unsigned short*)d_ws;                 // N*256 bf16 (h1; reused as agg2)
    unsigned short* o1_bf  = h_bf   + (size_t)NNODES * 256;         // N*64 bf16
    unsigned short* o2_bf  = o1_bf  + (size_t)NNODES * 64;          // N*64 bf16 (unused)
    unsigned short* W1T    = o2_bf  + (size_t)NNODES * 64;          // 256*128
    unsigned short* W2T    = W1T + 256 * 128;                       // 256*64
    float* z      = (float*)(W2T + 256 * 64);                       // N*200 f32
    float* out2_f = z      + (size_t)NNODES * MLP_HID;              // N*64 f32
    float* el     = out2_f + (size_t)NNODES * 64;                   // N*4
    float* er     = el     + (size_t)NNODES * 4;                    // N*4
    float* bn_sum   = er + (size_t)NNODES * 4;                      // 200
    float* bn_sumsq = bn_sum + MLP_HID;                             // 200
    int* cnt      = (int*)(bn_sumsq + MLP_HID);                     // N
    int* row_ptr  = cnt + NNODES;                                   // N+1
    int* cursor   = row_ptr + NNODES + 1;                           // N
    int* bsum     = cursor + NNODES;                                // 256
    int* boff     = bsum + 256;                                     // 256
    int* col_src  = boff + 256;                                     // E
    unsigned short* agg2 = h_bf;    // alias: h1 dead after layer-1 edge kernel

    const dim3 blk(256);
    const int eg = (E + 255) / 256;
    const int gb = (NNODES + 63) / 64;
    const int ng4 = (NNODES + 3) / 4;       // wave-per-node edge grid

    // ---- init (weight transposes + zeroing) ----
    init_all<<<INIT_BLOCKS, blk, 0, stream>>>(W1, W1T, W2, W2T, cnt, bn_sum);

    // ---- CSR build ----
    csr_count<<<eg, blk, 0, stream>>>(dst, cnt, E);
    csr_bsum<<<NB_SCAN, blk, 0, stream>>>(cnt, bsum);
    csr_bscan<<<1, blk, 0, stream>>>(bsum, boff);
    csr_fill<<<NB_SCAN, blk, 0, stream>>>(cnt, boff, row_ptr, cursor);
    csr_scatter<<<eg, blk, 0, stream>>>(src, dst, cursor, col_src, E);

    // ---- layer 1 ----
    mfma_gemm_attn<128, true, true><<<gb, blk, 0, stream>>>(
        feat, W1T, al1, ar1, h_bf, el, er, NNODES);
    gat_edge_v7<<<ng4, blk, 0, stream>>>(row_ptr, col_src, el, er, h_bf, b1,
                                         o1_bf, NNODES);

    // ---- layer 2 (aggregate in o1-space, then apply W2) ----
    mfma_gemm_attn<64, false, false><<<gb, blk, 0, stream>>>(
        o1_bf, W2T, al2, ar2, nullptr, el, er, NNODES);
    gat_edge_agg<<<ng4, blk, 0, stream>>>(row_ptr, col_src, el, er,
                                          o1_bf, agg2, NNODES);
    mfma_apply_w2<<<gb, blk, 0, stream>>>(agg2, W2T, b2, out2_f, NNODES);

    // ---- MLP (f32, fused BN partials) ----
    gemm_tile<64,true,true><<<dim3((MLP_HID + 63) / 64, gb), blk, 0, stream>>>(
        out2_f, Wm1, bm1, z, bn_sum, bn_sumsq, NNODES, MLP_HID);

    mlp2<<<(NNODES * 64 + 255) / 256, blk, 0, stream>>>(
        z, bn_sum, bn_sumsq, gamma, beta, Wm2, bm2, out, NNODES);
}

// Round 15
// 380.573 us; speedup vs baseline: 1.0240x; 1.0240x over previous
//
#include <hip/hip_runtime.h>
#include <hip/hip_bf16.h>

#define NNODES 50000
#define MLP_HID 200
#define NB_SCAN 196   // ceil(NNODES/256)
#define CAP 128       // per-node edge cache (mean degree ~17)

// init kernel block ranges
#define NB_W1   256
#define NB_W2   256
#define NB_WM1  208
#define NB_ZC   196
#define INIT_BLOCKS (NB_W1 + NB_W2 + NB_WM1 + NB_ZC + 1)

typedef __attribute__((ext_vector_type(8))) short bf16x8;
typedef __attribute__((ext_vector_type(4))) float f32x4;

__device__ __forceinline__ unsigned short f2bf(float x){
    unsigned u = __float_as_uint(x);
    unsigned r = (u + 0x7fffu + ((u >> 16) & 1u)) >> 16;
    return (unsigned short)r;
}
__device__ __forceinline__ float bflo(unsigned u){ return __uint_as_float(u << 16); }
__device__ __forceinline__ float bfhi(unsigned u){ return __uint_as_float(u & 0xffff0000u); }

// ---------------- init: W1T, W2T, Wm1T, zero cnt & bn accumulators -----------
__global__ __launch_bounds__(256) void init_all(
    const float* __restrict__ W1, unsigned short* __restrict__ W1T,
    const float* __restrict__ W2, unsigned short* __restrict__ W2T,
    const float* __restrict__ Wm1, unsigned short* __restrict__ Wm1T,
    int* __restrict__ cnt, float* __restrict__ bn_acc /*400 floats*/)
{
    const int b = blockIdx.x, tid = threadIdx.x;
    if (b < NB_W1){
        int c = b;
        if (tid < 128) W1T[(size_t)c * 128 + tid] = f2bf(W1[(size_t)tid * 256 + c]);
    } else if (b < NB_W1 + NB_W2){
        int c = b - NB_W1;
        if (tid < 64) W2T[(size_t)c * 64 + tid] = f2bf(W2[(size_t)tid * 256 + c]);
    } else if (b < NB_W1 + NB_W2 + NB_WM1){
        int c = b - NB_W1 - NB_W2;   // 0..207
        if (tid < 64)
            Wm1T[(size_t)c * 64 + tid] =
                (c < MLP_HID) ? f2bf(Wm1[(size_t)tid * MLP_HID + c]) : (unsigned short)0;
    } else if (b < NB_W1 + NB_W2 + NB_WM1 + NB_ZC){
        int i = (b - NB_W1 - NB_W2 - NB_WM1) * 256 + tid;
        if (i < NNODES) cnt[i] = 0;
    } else {
        if (tid < 2 * MLP_HID - 256) bn_acc[256 + tid] = 0.f;
        bn_acc[tid] = 0.f;
    }
}

// ---------------- MFMA GEMM + attn-dot epilogue ------------------------------
// F32IN: A is f32 (bf16-rounded in-register). STOREH: write h table.
template<int K, bool F32IN, bool STOREH>
__global__ __launch_bounds__(256) void mfma_gemm_attn(
    const void* __restrict__ Aptr,
    const unsigned short* __restrict__ WT,
    const float* __restrict__ al, const float* __restrict__ ar,
    unsigned short* __restrict__ hb,
    float* __restrict__ el, float* __restrict__ er, int M)
{
    const int wv = threadIdx.x >> 6, lane = threadIdx.x & 63;
    const int r0 = blockIdx.x * 64 + wv * 16;
    const int l15 = lane & 15, ks = lane >> 4;

    f32x4 acc[16];
    #pragma unroll
    for (int nt = 0; nt < 16; nt++)
        #pragma unroll
        for (int q = 0; q < 4; q++) acc[nt][q] = 0.f;

    const int arow = min(r0 + l15, M - 1);
    const unsigned short* aptr_b = (const unsigned short*)Aptr + (size_t)arow * K + ks * 8;
    const float*          aptr_f = (const float*)Aptr          + (size_t)arow * K + ks * 8;
    const unsigned short* bptr = WT + (size_t)l15 * K + ks * 8;

    #pragma unroll
    for (int k0 = 0; k0 < K; k0 += 32){
        bf16x8 a;
        if (F32IN){
            float4 f0 = *(const float4*)(aptr_f + k0);
            float4 f1 = *(const float4*)(aptr_f + k0 + 4);
            a[0] = (short)f2bf(f0.x); a[1] = (short)f2bf(f0.y);
            a[2] = (short)f2bf(f0.z); a[3] = (short)f2bf(f0.w);
            a[4] = (short)f2bf(f1.x); a[5] = (short)f2bf(f1.y);
            a[6] = (short)f2bf(f1.z); a[7] = (short)f2bf(f1.w);
        } else {
            a = *(const bf16x8*)(aptr_b + k0);
        }
        #pragma unroll
        for (int nt = 0; nt < 16; nt++){
            bf16x8 b = *(const bf16x8*)(bptr + (size_t)nt * 16 * K + k0);
            acc[nt] = __builtin_amdgcn_mfma_f32_16x16x32_bf16(a, b, acc[nt], 0, 0, 0);
        }
    }

    float elv[4][4], erv[4][4];
    #pragma unroll
    for (int r = 0; r < 4; r++)
        #pragma unroll
        for (int hh = 0; hh < 4; hh++){ elv[r][hh] = 0.f; erv[r][hh] = 0.f; }

    #pragma unroll
    for (int nt = 0; nt < 16; nt++){
        int col = nt * 16 + l15;
        float alv = al[col], arv = ar[col];
        #pragma unroll
        for (int reg = 0; reg < 4; reg++){
            elv[reg][nt >> 2] = fmaf(acc[nt][reg], alv, elv[reg][nt >> 2]);
            erv[reg][nt >> 2] = fmaf(acc[nt][reg], arv, erv[reg][nt >> 2]);
        }
    }
    #pragma unroll
    for (int o = 8; o > 0; o >>= 1){
        #pragma unroll
        for (int reg = 0; reg < 4; reg++)
            #pragma unroll
            for (int hh = 0; hh < 4; hh++){
                elv[reg][hh] += __shfl_xor(elv[reg][hh], o);
                erv[reg][hh] += __shfl_xor(erv[reg][hh], o);
            }
    }
    if (l15 == 0){
        #pragma unroll
        for (int reg = 0; reg < 4; reg++){
            int r = r0 + ks * 4 + reg;
            if (r < M){
                #pragma unroll
                for (int hh = 0; hh < 4; hh++){
                    el[r * 4 + hh] = elv[reg][hh];
                    er[r * 4 + hh] = erv[reg][hh];
                }
            }
        }
    }

    if constexpr (STOREH){
        __shared__ __align__(16) unsigned short hbuf[4][16][264];
        #pragma unroll
        for (int nt = 0; nt < 16; nt++)
            #pragma unroll
            for (int reg = 0; reg < 4; reg++)
                hbuf[wv][ks * 4 + reg][nt * 16 + l15] = f2bf(acc[nt][reg]);
        #pragma unroll
        for (int t = 0; t < 8; t++){
            int chunk = t * 64 + lane;
            int rr = chunk >> 5;
            int cc = (chunk & 31) * 8;
            int r = r0 + rr;
            if (r < M){
                uint4 v = *(const uint4*)&hbuf[wv][rr][cc];
                *(uint4*)&hb[(size_t)r * 256 + cc] = v;
            }
        }
    }
}

// ---------------- MFMA MLP: z = relu(o2 @ Wm1 + bm1), block-reduced BN -------
// A: [M][64] bf16; WT: [208][64] bf16; z: [M][200] f32.
// BN partials: per-wave shfl reduce -> LDS -> ONE atomicAdd per col per block.
__global__ __launch_bounds__(256) void mfma_mlp(
    const unsigned short* __restrict__ Abf,
    const unsigned short* __restrict__ WT,
    const float* __restrict__ bm1,
    float* __restrict__ z,
    float* __restrict__ bn_sum, float* __restrict__ bn_sumsq, int M)
{
    __shared__ float s_sum[4][208], s_ssq[4][208];
    const int wv = threadIdx.x >> 6, lane = threadIdx.x & 63;
    const int r0 = blockIdx.x * 64 + wv * 16;
    const int l15 = lane & 15, ks = lane >> 4;

    f32x4 acc[13];
    #pragma unroll
    for (int nt = 0; nt < 13; nt++)
        #pragma unroll
        for (int q = 0; q < 4; q++) acc[nt][q] = 0.f;

    const int arow = min(r0 + l15, M - 1);
    const unsigned short* aptr = Abf + (size_t)arow * 64 + ks * 8;
    const unsigned short* bptr = WT + (size_t)l15 * 64 + ks * 8;

    #pragma unroll
    for (int k0 = 0; k0 < 64; k0 += 32){
        bf16x8 a = *(const bf16x8*)(aptr + k0);
        #pragma unroll
        for (int nt = 0; nt < 13; nt++){
            bf16x8 b = *(const bf16x8*)(bptr + (size_t)nt * 16 * 64 + k0);
            acc[nt] = __builtin_amdgcn_mfma_f32_16x16x32_bf16(a, b, acc[nt], 0, 0, 0);
        }
    }

    #pragma unroll
    for (int nt = 0; nt < 13; nt++){
        int col = nt * 16 + l15;
        bool colok = col < MLP_HID;
        float bias = colok ? bm1[col] : 0.f;
        float cs = 0.f, css = 0.f;
        #pragma unroll
        for (int reg = 0; reg < 4; reg++){
            int r = r0 + ks * 4 + reg;
            float v = fmaxf(acc[nt][reg] + bias, 0.f);
            bool ok = colok && (r < M);
            if (ok) z[(size_t)r * MLP_HID + col] = v;
            float vv = ok ? v : 0.f;
            cs += vv; css += vv * vv;
        }
        // reduce across the 4 ks-groups (lane bits 4,5)
        cs  += __shfl_xor(cs, 16);  cs  += __shfl_xor(cs, 32);
        css += __shfl_xor(css, 16); css += __shfl_xor(css, 32);
        if (ks == 0 && colok){
            s_sum[wv][col] = cs;
            s_ssq[wv][col] = css;
        }
    }
    __syncthreads();
    if (threadIdx.x < MLP_HID){
        int c = threadIdx.x;
        float a = s_sum[0][c] + s_sum[1][c] + s_sum[2][c] + s_sum[3][c];
        float b = s_ssq[0][c] + s_ssq[1][c] + s_ssq[2][c] + s_ssq[3][c];
        atomicAdd(&bn_sum[c], a);
        atomicAdd(&bn_sumsq[c], b);
    }
}

// ---------------- CSR build (hierarchical scan) ----------------
__global__ __launch_bounds__(256) void csr_count(const int* __restrict__ dst,
                                                 int* __restrict__ cnt, int E){
    int e = blockIdx.x * blockDim.x + threadIdx.x;
    if (e < E) atomicAdd(&cnt[dst[e]], 1);
}

__global__ __launch_bounds__(256) void csr_bsum(const int* __restrict__ cnt,
                                                int* __restrict__ bsum){
    __shared__ int red[256];
    int i = blockIdx.x * 256 + threadIdx.x;
    red[threadIdx.x] = (i < NNODES) ? cnt[i] : 0;
    __syncthreads();
    for (int off = 128; off > 0; off >>= 1){
        if (threadIdx.x < off) red[threadIdx.x] += red[threadIdx.x + off];
        __syncthreads();
    }
    if (threadIdx.x == 0) bsum[blockIdx.x] = red[0];
}

__global__ __launch_bounds__(256) void csr_bscan(const int* __restrict__ bsum,
                                                 int* __restrict__ boff){
    __shared__ int part[256];
    int t = threadIdx.x;
    int v = (t < NB_SCAN) ? bsum[t] : 0;
    part[t] = v;
    __syncthreads();
    for (int off = 1; off < 256; off <<= 1){
        int u = (t >= off) ? part[t - off] : 0;
        __syncthreads();
        part[t] += u;
        __syncthreads();
    }
    if (t < NB_SCAN) boff[t] = part[t] - v;
}

__global__ __launch_bounds__(256) void csr_fill(const int* __restrict__ cnt,
                                                const int* __restrict__ boff,
                                                int* __restrict__ row_ptr,
                                                int* __restrict__ cursor){
    __shared__ int part[256];
    int b = blockIdx.x, t = threadIdx.x;
    int i = b * 256 + t;
    int c = (i < NNODES) ? cnt[i] : 0;
    part[t] = c;
    __syncthreads();
    for (int off = 1; off < 256; off <<= 1){
        int u = (t >= off) ? part[t - off] : 0;
        __syncthreads();
        part[t] += u;
        __syncthreads();
    }
    int excl = part[t] - c + boff[b];
    if (i < NNODES){ row_ptr[i] = excl; cursor[i] = excl; }
    if (i == NNODES - 1) row_ptr[NNODES] = excl + c;
}

__global__ __launch_bounds__(256) void csr_scatter(const int* __restrict__ src,
                                                   const int* __restrict__ dst,
                                                   int* __restrict__ cursor,
                                                   int* __restrict__ col_src, int E){
    int e = blockIdx.x * blockDim.x + threadIdx.x;
    if (e >= E) return;
    int pos = atomicAdd(&cursor[dst[e]], 1);
    col_src[pos] = src[e];
}

// ---------------- edge kernel v7: one wave per node, 4-deep gather -----------
__global__ __launch_bounds__(256) void gat_edge_v7(
    const int* __restrict__ row_ptr, const int* __restrict__ col_src,
    const float* __restrict__ el, const float* __restrict__ er,
    const unsigned short* __restrict__ hb, const float* __restrict__ bias,
    unsigned short* __restrict__ out_b, int N)
{
    __shared__ float s_w[4][4][132];
    __shared__ int   s_idx[4][CAP];

    const int wv = threadIdx.x >> 6;
    const int lane = threadIdx.x & 63;
    const int n = blockIdx.x * 4 + wv;
    if (n >= N) return;

    const int rs = row_ptr[n], re = row_ptr[n + 1];
    const int K = re - rs;
    const float4 ern = *(const float4*)&er[n * 4];
    float (*sw)[132] = s_w[wv];
    int* sidx = s_idx[wv];

    float ls0 = 0.f, ls1 = 0.f, ls2 = 0.f, ls3 = 0.f;
    for (int k = lane; k < K; k += 64){
        int s = col_src[rs + k];
        float4 e4 = *(const float4*)&el[s * 4];
        float e0 = e4.x + ern.x; e0 = (e0 >= 0.f) ? e0 : 0.2f * e0;
        float e1 = e4.y + ern.y; e1 = (e1 >= 0.f) ? e1 : 0.2f * e1;
        float e2 = e4.z + ern.z; e2 = (e2 >= 0.f) ? e2 : 0.2f * e2;
        float e3 = e4.w + ern.w; e3 = (e3 >= 0.f) ? e3 : 0.2f * e3;
        float w0 = __expf(e0), w1 = __expf(e1), w2 = __expf(e2), w3 = __expf(e3);
        if (k < CAP){
            sidx[k] = s;
            sw[0][k] = w0; sw[1][k] = w1; sw[2][k] = w2; sw[3][k] = w3;
        }
        ls0 += w0; ls1 += w1; ls2 += w2; ls3 += w3;
    }
    #pragma unroll
    for (int o = 32; o > 0; o >>= 1){
        ls0 += __shfl_xor(ls0, o); ls1 += __shfl_xor(ls1, o);
        ls2 += __shfl_xor(ls2, o); ls3 += __shfl_xor(ls3, o);
    }
    const int slot = lane >> 5;
    const int c8   = (lane & 31) * 8;
    const int hc   = c8 >> 6;
    const float invh = 1.f / (hc == 0 ? ls0 : hc == 1 ? ls1 : hc == 2 ? ls2 : ls3);

    float acc[8];
    #pragma unroll
    for (int q = 0; q < 8; q++) acc[q] = 0.f;

    for (int base = 0; base < K; base += CAP){
        if (base > 0){
            for (int k = base + lane; k < min(K, base + CAP); k += 64){
                int s = col_src[rs + k];
                float4 e4 = *(const float4*)&el[s * 4];
                float e0 = e4.x + ern.x; e0 = (e0 >= 0.f) ? e0 : 0.2f * e0;
                float e1 = e4.y + ern.y; e1 = (e1 >= 0.f) ? e1 : 0.2f * e1;
                float e2 = e4.z + ern.z; e2 = (e2 >= 0.f) ? e2 : 0.2f * e2;
                float e3 = e4.w + ern.w; e3 = (e3 >= 0.f) ? e3 : 0.2f * e3;
                int kk = k - base;
                sidx[kk] = s;
                sw[0][kk] = __expf(e0); sw[1][kk] = __expf(e1);
                sw[2][kk] = __expf(e2); sw[3][kk] = __expf(e3);
            }
        }
        const int rem = min(CAP, K - base);
        for (int j = slot; j < rem; j += 8){
            int   j1 = j + 2, j2 = j + 4, j3 = j + 6;
            int   jc1 = min(j1, rem - 1), jc2 = min(j2, rem - 1), jc3 = min(j3, rem - 1);
            float w0v = sw[hc][j];
            float w1v = (j1 < rem) ? sw[hc][j1] : 0.f;
            float w2v = (j2 < rem) ? sw[hc][j2] : 0.f;
            float w3v = (j3 < rem) ? sw[hc][j3] : 0.f;
            int   s0 = sidx[j], s1 = sidx[jc1], s2 = sidx[jc2], s3 = sidx[jc3];
            uint4 v0 = *(const uint4*)&hb[(size_t)s0 * 256 + c8];
            uint4 v1 = *(const uint4*)&hb[(size_t)s1 * 256 + c8];
            uint4 v2 = *(const uint4*)&hb[(size_t)s2 * 256 + c8];
            uint4 v3 = *(const uint4*)&hb[(size_t)s3 * 256 + c8];
            acc[0] = fmaf(w0v, bflo(v0.x), acc[0]); acc[1] = fmaf(w0v, bfhi(v0.x), acc[1]);
            acc[2] = fmaf(w0v, bflo(v0.y), acc[2]); acc[3] = fmaf(w0v, bfhi(v0.y), acc[3]);
            acc[4] = fmaf(w0v, bflo(v0.z), acc[4]); acc[5] = fmaf(w0v, bfhi(v0.z), acc[5]);
            acc[6] = fmaf(w0v, bflo(v0.w), acc[6]); acc[7] = fmaf(w0v, bfhi(v0.w), acc[7]);
            acc[0] = fmaf(w1v, bflo(v1.x), acc[0]); acc[1] = fmaf(w1v, bfhi(v1.x), acc[1]);
            acc[2] = fmaf(w1v, bflo(v1.y), acc[2]); acc[3] = fmaf(w1v, bfhi(v1.y), acc[3]);
            acc[4] = fmaf(w1v, bflo(v1.z), acc[4]); acc[5] = fmaf(w1v, bfhi(v1.z), acc[5]);
            acc[6] = fmaf(w1v, bflo(v1.w), acc[6]); acc[7] = fmaf(w1v, bfhi(v1.w), acc[7]);
            acc[0] = fmaf(w2v, bflo(v2.x), acc[0]); acc[1] = fmaf(w2v, bfhi(v2.x), acc[1]);
            acc[2] = fmaf(w2v, bflo(v2.y), acc[2]); acc[3] = fmaf(w2v, bfhi(v2.y), acc[3]);
            acc[4] = fmaf(w2v, bflo(v2.z), acc[4]); acc[5] = fmaf(w2v, bfhi(v2.z), acc[5]);
            acc[6] = fmaf(w2v, bflo(v2.w), acc[6]); acc[7] = fmaf(w2v, bfhi(v2.w), acc[7]);
            acc[0] = fmaf(w3v, bflo(v3.x), acc[0]); acc[1] = fmaf(w3v, bfhi(v3.x), acc[1]);
            acc[2] = fmaf(w3v, bflo(v3.y), acc[2]); acc[3] = fmaf(w3v, bfhi(v3.y), acc[3]);
            acc[4] = fmaf(w3v, bflo(v3.z), acc[4]); acc[5] = fmaf(w3v, bfhi(v3.z), acc[5]);
            acc[6] = fmaf(w3v, bflo(v3.w), acc[6]); acc[7] = fmaf(w3v, bfhi(v3.w), acc[7]);
        }
    }

    #pragma unroll
    for (int q = 0; q < 8; q++){
        acc[q] *= invh;
        acc[q] += __shfl_xor(acc[q], 32);
        acc[q] = fmaxf(acc[q] + bias[c8 + q], 0.f);
        acc[q] += __shfl_xor(acc[q], 8);
        acc[q] += __shfl_xor(acc[q], 16);
        acc[q] *= 0.25f;
    }
    if (lane < 8){
        uint4 pb;
        pb.x = (unsigned)f2bf(acc[0]) | ((unsigned)f2bf(acc[1]) << 16);
        pb.y = (unsigned)f2bf(acc[2]) | ((unsigned)f2bf(acc[3]) << 16);
        pb.z = (unsigned)f2bf(acc[4]) | ((unsigned)f2bf(acc[5]) << 16);
        pb.w = (unsigned)f2bf(acc[6]) | ((unsigned)f2bf(acc[7]) << 16);
        *(uint4*)&out_b[(size_t)n * 64 + lane * 8] = pb;
    }
}

// ---------------- final linear (BN scale/shift computed inline) --------------
__global__ __launch_bounds__(256) void mlp2(const float* __restrict__ z,
                                            const float* __restrict__ bn_sum,
                                            const float* __restrict__ bn_sumsq,
                                            const float* __restrict__ gamma,
                                            const float* __restrict__ beta,
                                            const float* __restrict__ Wm2,
                                            const float* __restrict__ bm2,
                                            float* __restrict__ out,
                                            int Nrows){
    __shared__ float s_scale[MLP_HID], s_shift[MLP_HID];
    const int tid = threadIdx.x;
    if (tid < MLP_HID){
        float inv = 1.f / (float)Nrows;
        float mu = bn_sum[tid] * inv;
        float var = bn_sumsq[tid] * inv - mu * mu;
        float rstd = rsqrtf(var + 1e-5f);
        float sc = rstd * gamma[tid];
        s_scale[tid] = sc;
        s_shift[tid] = beta[tid] - mu * sc;
    }
    __syncthreads();
    int n = (blockIdx.x * 256 + tid) >> 6;
    if (n >= Nrows) return;
    int lane = tid & 63;
    float a0 = 0.f, a1 = 0.f;
    for (int k = lane; k < MLP_HID; k += 64){
        float zn = z[(size_t)n * MLP_HID + k] * s_scale[k] + s_shift[k];
        a0 = fmaf(zn, Wm2[k * 2 + 0], a0);
        a1 = fmaf(zn, Wm2[k * 2 + 1], a1);
    }
    #pragma unroll
    for (int o = 32; o > 0; o >>= 1){
        a0 += __shfl_xor(a0, o);
        a1 += __shfl_xor(a1, o);
    }
    if (lane == 0){
        out[n * 2 + 0] = a0 + bm2[0];
        out[n * 2 + 1] = a1 + bm2[1];
    }
}

extern "C" void kernel_launch(void* const* d_in, const int* in_sizes, int n_in,
                              void* d_out, int out_size, void* d_ws, size_t ws_size,
                              hipStream_t stream) {
    const float* feat  = (const float*)d_in[0];
    const int*   src   = (const int*)  d_in[1];
    const int*   dst   = (const int*)  d_in[2];
    const float* W1    = (const float*)d_in[3];
    const float* al1   = (const float*)d_in[4];
    const float* ar1   = (const float*)d_in[5];
    const float* b1    = (const float*)d_in[6];
    const float* W2    = (const float*)d_in[7];
    const float* al2   = (const float*)d_in[8];
    const float* ar2   = (const float*)d_in[9];
    const float* b2    = (const float*)d_in[10];
    const float* Wm1   = (const float*)d_in[11];
    const float* bm1   = (const float*)d_in[12];
    const float* gamma = (const float*)d_in[13];
    const float* beta  = (const float*)d_in[14];
    const float* Wm2   = (const float*)d_in[15];
    const float* bm2   = (const float*)d_in[16];
    const int E = in_sizes[1];
    float* out = (float*)d_out;

    // ---- workspace layout ----
    unsigned short* h_bf   = (unsigned short*)d_ws;                 // N*256 bf16
    unsigned short* o1_bf  = h_bf   + (size_t)NNODES * 256;         // N*64 bf16
    unsigned short* o2_bf  = o1_bf  + (size_t)NNODES * 64;          // N*64 bf16
    unsigned short* W1T    = o2_bf  + (size_t)NNODES * 64;          // 256*128
    unsigned short* W2T    = W1T + 256 * 128;                       // 256*64
    unsigned short* Wm1T   = W2T + 256 * 64;                        // 208*64
    float* z      = (float*)(Wm1T + 208 * 64);                      // N*200 f32
    float* el     = z      + (size_t)NNODES * MLP_HID;              // N*4
    float* er     = el     + (size_t)NNODES * 4;                    // N*4
    float* bn_sum   = er + (size_t)NNODES * 4;                      // 200
    float* bn_sumsq = bn_sum + MLP_HID;                             // 200
    int* cnt      = (int*)(bn_sumsq + MLP_HID);                     // N
    int* row_ptr  = cnt + NNODES;                                   // N+1
    int* cursor   = row_ptr + NNODES + 1;                           // N
    int* bsum     = cursor + NNODES;                                // 256
    int* boff     = bsum + 256;                                     // 256
    int* col_src  = boff + 256;                                     // E

    const dim3 blk(256);
    const int eg = (E + 255) / 256;
    const int gb = (NNODES + 63) / 64;
    const int ng4 = (NNODES + 3) / 4;       // wave-per-node edge grid

    // ---- init (weight transposes + zeroing) ----
    init_all<<<INIT_BLOCKS, blk, 0, stream>>>(W1, W1T, W2, W2T, Wm1, Wm1T,
                                              cnt, bn_sum);

    // ---- CSR build ----
    csr_count<<<eg, blk, 0, stream>>>(dst, cnt, E);
    csr_bsum<<<NB_SCAN, blk, 0, stream>>>(cnt, bsum);
    csr_bscan<<<1, blk, 0, stream>>>(bsum, boff);
    csr_fill<<<NB_SCAN, blk, 0, stream>>>(cnt, boff, row_ptr, cursor);
    csr_scatter<<<eg, blk, 0, stream>>>(src, dst, cursor, col_src, E);

    // ---- layer 1 (f32 feat read directly, in-register bf16 pack) ----
    mfma_gemm_attn<128, true, true><<<gb, blk, 0, stream>>>(
        feat, W1T, al1, ar1, h_bf, el, er, NNODES);
    gat_edge_v7<<<ng4, blk, 0, stream>>>(row_ptr, col_src, el, er, h_bf, b1,
                                         o1_bf, NNODES);

    // ---- layer 2 ----
    mfma_gemm_attn<64, false, true><<<gb, blk, 0, stream>>>(
        o1_bf, W2T, al2, ar2, h_bf, el, er, NNODES);
    gat_edge_v7<<<ng4, blk, 0, stream>>>(row_ptr, col_src, el, er, h_bf, b2,
                                         o2_bf, NNODES);

    // ---- MLP (MFMA, block-reduced BN partials) ----
    mfma_mlp<<<gb, blk, 0, stream>>>(o2_bf, Wm1T, bm1, z, bn_sum, bn_sumsq, NNODES);

    mlp2<<<(NNODES * 64 + 255) / 256, blk, 0, stream>>>(
        z, bn_sum, bn_sumsq, gamma, beta, Wm2, bm2, out, NNODES);
}

// Round 16
// 365.779 us; speedup vs baseline: 1.0654x; 1.0404x over previous
//
#include <hip/hip_runtime.h>
#include <hip/hip_bf16.h>

#define NNODES 50000
#define MLP_HID 200
#define NB_SCAN 196   // ceil(NNODES/256)
#define CAP 128       // per-node edge cache (mean degree ~17)

// init kernel block ranges (feat conversion removed: layer-1 GEMM reads f32)
#define NB_W1   256
#define NB_W2   256
#define NB_ZC   196
#define INIT_BLOCKS (NB_W1 + NB_W2 + NB_ZC + 1)

typedef __attribute__((ext_vector_type(8))) short bf16x8;
typedef __attribute__((ext_vector_type(4))) float f32x4;

__device__ __forceinline__ unsigned short f2bf(float x){
    unsigned u = __float_as_uint(x);
    unsigned r = (u + 0x7fffu + ((u >> 16) & 1u)) >> 16;
    return (unsigned short)r;
}
__device__ __forceinline__ float bflo(unsigned u){ return __uint_as_float(u << 16); }
__device__ __forceinline__ float bfhi(unsigned u){ return __uint_as_float(u & 0xffff0000u); }

// ---------------- init: W1T, W2T, zero cnt & bn accumulators -----------------
__global__ __launch_bounds__(256) void init_all(
    const float* __restrict__ W1, unsigned short* __restrict__ W1T,
    const float* __restrict__ W2, unsigned short* __restrict__ W2T,
    int* __restrict__ cnt, float* __restrict__ bn_acc /*400 floats*/)
{
    const int b = blockIdx.x, tid = threadIdx.x;
    if (b < NB_W1){
        int c = b;
        if (tid < 128) W1T[(size_t)c * 128 + tid] = f2bf(W1[(size_t)tid * 256 + c]);
    } else if (b < NB_W1 + NB_W2){
        int c = b - NB_W1;
        if (tid < 64) W2T[(size_t)c * 64 + tid] = f2bf(W2[(size_t)tid * 256 + c]);
    } else if (b < NB_W1 + NB_W2 + NB_ZC){
        int i = (b - NB_W1 - NB_W2) * 256 + tid;
        if (i < NNODES) cnt[i] = 0;
    } else {
        if (tid < 2 * MLP_HID - 256) bn_acc[256 + tid] = 0.f;
        bn_acc[tid] = 0.f;
    }
}

// ---------------- MFMA GEMM + attn-dot epilogue ------------------------------
// F32IN: A is f32 (converted to bf16 in-register, same rounding as init path).
template<int K, bool F32IN>
__global__ __launch_bounds__(256) void mfma_gemm_attn(
    const void* __restrict__ Aptr,
    const unsigned short* __restrict__ WT,
    const float* __restrict__ al, const float* __restrict__ ar,
    unsigned short* __restrict__ hb,
    float* __restrict__ el, float* __restrict__ er, int M)
{
    const int wv = threadIdx.x >> 6, lane = threadIdx.x & 63;
    const int r0 = blockIdx.x * 64 + wv * 16;
    const int l15 = lane & 15, ks = lane >> 4;

    f32x4 acc[16];
    #pragma unroll
    for (int nt = 0; nt < 16; nt++)
        #pragma unroll
        for (int q = 0; q < 4; q++) acc[nt][q] = 0.f;

    const int arow = min(r0 + l15, M - 1);
    const unsigned short* aptr_b = (const unsigned short*)Aptr + (size_t)arow * K + ks * 8;
    const float*          aptr_f = (const float*)Aptr          + (size_t)arow * K + ks * 8;
    const unsigned short* bptr = WT + (size_t)l15 * K + ks * 8;

    #pragma unroll
    for (int k0 = 0; k0 < K; k0 += 32){
        bf16x8 a;
        if (F32IN){
            float4 f0 = *(const float4*)(aptr_f + k0);
            float4 f1 = *(const float4*)(aptr_f + k0 + 4);
            a[0] = (short)f2bf(f0.x); a[1] = (short)f2bf(f0.y);
            a[2] = (short)f2bf(f0.z); a[3] = (short)f2bf(f0.w);
            a[4] = (short)f2bf(f1.x); a[5] = (short)f2bf(f1.y);
            a[6] = (short)f2bf(f1.z); a[7] = (short)f2bf(f1.w);
        } else {
            a = *(const bf16x8*)(aptr_b + k0);
        }
        #pragma unroll
        for (int nt = 0; nt < 16; nt++){
            bf16x8 b = *(const bf16x8*)(bptr + (size_t)nt * 16 * K + k0);
            acc[nt] = __builtin_amdgcn_mfma_f32_16x16x32_bf16(a, b, acc[nt], 0, 0, 0);
        }
    }

    float elv[4][4], erv[4][4];
    #pragma unroll
    for (int r = 0; r < 4; r++)
        #pragma unroll
        for (int hh = 0; hh < 4; hh++){ elv[r][hh] = 0.f; erv[r][hh] = 0.f; }

    #pragma unroll
    for (int nt = 0; nt < 16; nt++){
        int col = nt * 16 + l15;
        float alv = al[col], arv = ar[col];
        #pragma unroll
        for (int reg = 0; reg < 4; reg++){
            elv[reg][nt >> 2] = fmaf(acc[nt][reg], alv, elv[reg][nt >> 2]);
            erv[reg][nt >> 2] = fmaf(acc[nt][reg], arv, erv[reg][nt >> 2]);
        }
    }
    #pragma unroll
    for (int o = 8; o > 0; o >>= 1){
        #pragma unroll
        for (int reg = 0; reg < 4; reg++)
            #pragma unroll
            for (int hh = 0; hh < 4; hh++){
                elv[reg][hh] += __shfl_xor(elv[reg][hh], o);
                erv[reg][hh] += __shfl_xor(erv[reg][hh], o);
            }
    }
    if (l15 == 0){
        #pragma unroll
        for (int reg = 0; reg < 4; reg++){
            int r = r0 + ks * 4 + reg;
            if (r < M){
                #pragma unroll
                for (int hh = 0; hh < 4; hh++){
                    el[r * 4 + hh] = elv[reg][hh];
                    er[r * 4 + hh] = erv[reg][hh];
                }
            }
        }
    }

    __shared__ __align__(16) unsigned short hbuf[4][16][264];
    #pragma unroll
    for (int nt = 0; nt < 16; nt++)
        #pragma unroll
        for (int reg = 0; reg < 4; reg++)
            hbuf[wv][ks * 4 + reg][nt * 16 + l15] = f2bf(acc[nt][reg]);
    #pragma unroll
    for (int t = 0; t < 8; t++){
        int chunk = t * 64 + lane;
        int rr = chunk >> 5;
        int cc = (chunk & 31) * 8;
        int r = r0 + rr;
        if (r < M){
            uint4 v = *(const uint4*)&hbuf[wv][rr][cc];
            *(uint4*)&hb[(size_t)r * 256 + cc] = v;
        }
    }
}

// ---------------- f32 GEMM (MLP layer): +bias +relu, fused BN partials -------
template<int KT, bool RELU, bool BN>
__global__ __launch_bounds__(256) void gemm_tile(const float* __restrict__ A,
                                                 const float* __restrict__ B,
                                                 const float* __restrict__ bias,
                                                 float* __restrict__ C,
                                                 float* __restrict__ bn_sum,
                                                 float* __restrict__ bn_sumsq,
                                                 int M, int Nc){
    __shared__ float As[16][64];
    __shared__ float Bs[16][64];
    __shared__ float bnred[16][64];
    const int tid = threadIdx.x;
    const int tx = tid & 15, ty = tid >> 4;
    const int r0 = blockIdx.y * 64, c0 = blockIdx.x * 64;
    float acc[4][4] = {};
    const int lr  = tid >> 2,  lk4 = (tid & 3) * 4;
    const int bk  = tid >> 4,  bc4 = (tid & 15) * 4;

    for (int k0 = 0; k0 < KT; k0 += 16){
        float4 av = make_float4(0.f,0.f,0.f,0.f);
        if (r0 + lr < M) av = *(const float4*)&A[(size_t)(r0 + lr) * KT + k0 + lk4];
        As[lk4+0][lr] = av.x; As[lk4+1][lr] = av.y;
        As[lk4+2][lr] = av.z; As[lk4+3][lr] = av.w;

        if (c0 + bc4 + 3 < Nc){
            float4 bv = *(const float4*)&B[(size_t)(k0 + bk) * Nc + c0 + bc4];
            Bs[bk][bc4+0] = bv.x; Bs[bk][bc4+1] = bv.y;
            Bs[bk][bc4+2] = bv.z; Bs[bk][bc4+3] = bv.w;
        } else {
            #pragma unroll
            for (int j = 0; j < 4; j++){
                int c = c0 + bc4 + j;
                Bs[bk][bc4+j] = (c < Nc) ? B[(size_t)(k0 + bk) * Nc + c] : 0.f;
            }
        }
        __syncthreads();
        #pragma unroll
        for (int kk = 0; kk < 16; kk++){
            float4 a = *(const float4*)&As[kk][ty*4];
            float4 b = *(const float4*)&Bs[kk][tx*4];
            float arr[4] = {a.x,a.y,a.z,a.w};
            float brr[4] = {b.x,b.y,b.z,b.w};
            #pragma unroll
            for (int i = 0; i < 4; i++)
                #pragma unroll
                for (int j = 0; j < 4; j++)
                    acc[i][j] = fmaf(arr[i], brr[j], acc[i][j]);
        }
        __syncthreads();
    }

    float cs[4] = {0,0,0,0}, css[4] = {0,0,0,0};
    #pragma unroll
    for (int i = 0; i < 4; i++){
        int r = r0 + ty*4 + i;
        bool rok = r < M;
        #pragma unroll
        for (int j = 0; j < 4; j++){
            int c = c0 + tx*4 + j;
            if (c >= Nc) continue;
            float v = acc[i][j];
            if (bias) v += bias[c];
            if (RELU) v = fmaxf(v, 0.f);
            if (rok){
                C[(size_t)r * Nc + c] = v;
                if (BN){ cs[j] += v; css[j] += v * v; }
            }
        }
    }
    if (BN){
        #pragma unroll
        for (int j = 0; j < 4; j++) bnred[ty][tx*4+j] = cs[j];
        __syncthreads();
        if (tid < 64){
            float s = 0.f;
            #pragma unroll
            for (int t = 0; t < 16; t++) s += bnred[t][tid];
            if (c0 + tid < Nc) atomicAdd(&bn_sum[c0 + tid], s);
        }
        __syncthreads();
        #pragma unroll
        for (int j = 0; j < 4; j++) bnred[ty][tx*4+j] = css[j];
        __syncthreads();
        if (tid < 64){
            float s = 0.f;
            #pragma unroll
            for (int t = 0; t < 16; t++) s += bnred[t][tid];
            if (c0 + tid < Nc) atomicAdd(&bn_sumsq[c0 + tid], s);
        }
    }
}

// ---------------- CSR build (hierarchical scan) ----------------
__global__ __launch_bounds__(256) void csr_count(const int* __restrict__ dst,
                                                 int* __restrict__ cnt, int E){
    int e = blockIdx.x * blockDim.x + threadIdx.x;
    if (e < E) atomicAdd(&cnt[dst[e]], 1);
}

__global__ __launch_bounds__(256) void csr_bsum(const int* __restrict__ cnt,
                                                int* __restrict__ bsum){
    __shared__ int red[256];
    int i = blockIdx.x * 256 + threadIdx.x;
    red[threadIdx.x] = (i < NNODES) ? cnt[i] : 0;
    __syncthreads();
    for (int off = 128; off > 0; off >>= 1){
        if (threadIdx.x < off) red[threadIdx.x] += red[threadIdx.x + off];
        __syncthreads();
    }
    if (threadIdx.x == 0) bsum[blockIdx.x] = red[0];
}

__global__ __launch_bounds__(256) void csr_bscan(const int* __restrict__ bsum,
                                                 int* __restrict__ boff){
    __shared__ int part[256];
    int t = threadIdx.x;
    int v = (t < NB_SCAN) ? bsum[t] : 0;
    part[t] = v;
    __syncthreads();
    for (int off = 1; off < 256; off <<= 1){
        int u = (t >= off) ? part[t - off] : 0;
        __syncthreads();
        part[t] += u;
        __syncthreads();
    }
    if (t < NB_SCAN) boff[t] = part[t] - v;
}

__global__ __launch_bounds__(256) void csr_fill(const int* __restrict__ cnt,
                                                const int* __restrict__ boff,
                                                int* __restrict__ row_ptr,
                                                int* __restrict__ cursor){
    __shared__ int part[256];
    int b = blockIdx.x, t = threadIdx.x;
    int i = b * 256 + t;
    int c = (i < NNODES) ? cnt[i] : 0;
    part[t] = c;
    __syncthreads();
    for (int off = 1; off < 256; off <<= 1){
        int u = (t >= off) ? part[t - off] : 0;
        __syncthreads();
        part[t] += u;
        __syncthreads();
    }
    int excl = part[t] - c + boff[b];
    if (i < NNODES){ row_ptr[i] = excl; cursor[i] = excl; }
    if (i == NNODES - 1) row_ptr[NNODES] = excl + c;
}

__global__ __launch_bounds__(256) void csr_scatter(const int* __restrict__ src,
                                                   const int* __restrict__ dst,
                                                   int* __restrict__ cursor,
                                                   int* __restrict__ col_src, int E){
    int e = blockIdx.x * blockDim.x + threadIdx.x;
    if (e >= E) return;
    int pos = atomicAdd(&cursor[dst[e]], 1);
    col_src[pos] = src[e];
}

// ---------------- edge kernel v7: one wave per node, 4-deep gather -----------
// Clamped-index/zero-weight tail: no branchy tails, 4 independent 16B loads
// in flight per lane.
__global__ __launch_bounds__(256) void gat_edge_v7(
    const int* __restrict__ row_ptr, const int* __restrict__ col_src,
    const float* __restrict__ el, const float* __restrict__ er,
    const unsigned short* __restrict__ hb, const float* __restrict__ bias,
    float* __restrict__ out_f, unsigned short* __restrict__ out_b, int N)
{
    __shared__ float s_w[4][4][132];   // [wave][head][col] stride 132 -> conflict-free
    __shared__ int   s_idx[4][CAP];

    const int wv = threadIdx.x >> 6;
    const int lane = threadIdx.x & 63;
    const int n = blockIdx.x * 4 + wv;
    if (n >= N) return;

    const int rs = row_ptr[n], re = row_ptr[n + 1];
    const int K = re - rs;
    const float4 ern = *(const float4*)&er[n * 4];
    float (*sw)[132] = s_w[wv];
    int* sidx = s_idx[wv];

    // phase 1: exp weights (max-free: |e| bounded), cache first CAP, sums
    float ls0 = 0.f, ls1 = 0.f, ls2 = 0.f, ls3 = 0.f;
    for (int k = lane; k < K; k += 64){
        int s = col_src[rs + k];
        float4 e4 = *(const float4*)&el[s * 4];
        float e0 = e4.x + ern.x; e0 = (e0 >= 0.f) ? e0 : 0.2f * e0;
        float e1 = e4.y + ern.y; e1 = (e1 >= 0.f) ? e1 : 0.2f * e1;
        float e2 = e4.z + ern.z; e2 = (e2 >= 0.f) ? e2 : 0.2f * e2;
        float e3 = e4.w + ern.w; e3 = (e3 >= 0.f) ? e3 : 0.2f * e3;
        float w0 = __expf(e0), w1 = __expf(e1), w2 = __expf(e2), w3 = __expf(e3);
        if (k < CAP){
            sidx[k] = s;
            sw[0][k] = w0; sw[1][k] = w1; sw[2][k] = w2; sw[3][k] = w3;
        }
        ls0 += w0; ls1 += w1; ls2 += w2; ls3 += w3;
    }
    #pragma unroll
    for (int o = 32; o > 0; o >>= 1){
        ls0 += __shfl_xor(ls0, o); ls1 += __shfl_xor(ls1, o);
        ls2 += __shfl_xor(ls2, o); ls3 += __shfl_xor(ls3, o);
    }
    const int slot = lane >> 5;           // 0/1 half-wave
    const int c8   = (lane & 31) * 8;     // head*64 + dim0
    const int hc   = c8 >> 6;
    const float invh = 1.f / (hc == 0 ? ls0 : hc == 1 ? ls1 : hc == 2 ? ls2 : ls3);

    // phase 2: weighted gather, 4 edges in flight per half-wave
    float acc[8];
    #pragma unroll
    for (int q = 0; q < 8; q++) acc[q] = 0.f;

    for (int base = 0; base < K; base += CAP){
        if (base > 0){                    // rare refill (K > CAP)
            for (int k = base + lane; k < min(K, base + CAP); k += 64){
                int s = col_src[rs + k];
                float4 e4 = *(const float4*)&el[s * 4];
                float e0 = e4.x + ern.x; e0 = (e0 >= 0.f) ? e0 : 0.2f * e0;
                float e1 = e4.y + ern.y; e1 = (e1 >= 0.f) ? e1 : 0.2f * e1;
                float e2 = e4.z + ern.z; e2 = (e2 >= 0.f) ? e2 : 0.2f * e2;
                float e3 = e4.w + ern.w; e3 = (e3 >= 0.f) ? e3 : 0.2f * e3;
                int kk = k - base;
                sidx[kk] = s;
                sw[0][kk] = __expf(e0); sw[1][kk] = __expf(e1);
                sw[2][kk] = __expf(e2); sw[3][kk] = __expf(e3);
            }
        }
        const int rem = min(CAP, K - base);
        for (int j = slot; j < rem; j += 8){
            int   j1 = j + 2, j2 = j + 4, j3 = j + 6;
            int   jc1 = min(j1, rem - 1), jc2 = min(j2, rem - 1), jc3 = min(j3, rem - 1);
            float w0v = sw[hc][j];
            float w1v = (j1 < rem) ? sw[hc][j1] : 0.f;
            float w2v = (j2 < rem) ? sw[hc][j2] : 0.f;
            float w3v = (j3 < rem) ? sw[hc][j3] : 0.f;
            int   s0 = sidx[j], s1 = sidx[jc1], s2 = sidx[jc2], s3 = sidx[jc3];
            uint4 v0 = *(const uint4*)&hb[(size_t)s0 * 256 + c8];
            uint4 v1 = *(const uint4*)&hb[(size_t)s1 * 256 + c8];
            uint4 v2 = *(const uint4*)&hb[(size_t)s2 * 256 + c8];
            uint4 v3 = *(const uint4*)&hb[(size_t)s3 * 256 + c8];
            acc[0] = fmaf(w0v, bflo(v0.x), acc[0]); acc[1] = fmaf(w0v, bfhi(v0.x), acc[1]);
            acc[2] = fmaf(w0v, bflo(v0.y), acc[2]); acc[3] = fmaf(w0v, bfhi(v0.y), acc[3]);
            acc[4] = fmaf(w0v, bflo(v0.z), acc[4]); acc[5] = fmaf(w0v, bfhi(v0.z), acc[5]);
            acc[6] = fmaf(w0v, bflo(v0.w), acc[6]); acc[7] = fmaf(w0v, bfhi(v0.w), acc[7]);
            acc[0] = fmaf(w1v, bflo(v1.x), acc[0]); acc[1] = fmaf(w1v, bfhi(v1.x), acc[1]);
            acc[2] = fmaf(w1v, bflo(v1.y), acc[2]); acc[3] = fmaf(w1v, bfhi(v1.y), acc[3]);
            acc[4] = fmaf(w1v, bflo(v1.z), acc[4]); acc[5] = fmaf(w1v, bfhi(v1.z), acc[5]);
            acc[6] = fmaf(w1v, bflo(v1.w), acc[6]); acc[7] = fmaf(w1v, bfhi(v1.w), acc[7]);
            acc[0] = fmaf(w2v, bflo(v2.x), acc[0]); acc[1] = fmaf(w2v, bfhi(v2.x), acc[1]);
            acc[2] = fmaf(w2v, bflo(v2.y), acc[2]); acc[3] = fmaf(w2v, bfhi(v2.y), acc[3]);
            acc[4] = fmaf(w2v, bflo(v2.z), acc[4]); acc[5] = fmaf(w2v, bfhi(v2.z), acc[5]);
            acc[6] = fmaf(w2v, bflo(v2.w), acc[6]); acc[7] = fmaf(w2v, bfhi(v2.w), acc[7]);
            acc[0] = fmaf(w3v, bflo(v3.x), acc[0]); acc[1] = fmaf(w3v, bfhi(v3.x), acc[1]);
            acc[2] = fmaf(w3v, bflo(v3.y), acc[2]); acc[3] = fmaf(w3v, bfhi(v3.y), acc[3]);
            acc[4] = fmaf(w3v, bflo(v3.z), acc[4]); acc[5] = fmaf(w3v, bfhi(v3.z), acc[5]);
            acc[6] = fmaf(w3v, bflo(v3.w), acc[6]); acc[7] = fmaf(w3v, bfhi(v3.w), acc[7]);
        }
    }

    // normalize + slot reduce + bias/relu + head mean (all in-wave)
    #pragma unroll
    for (int q = 0; q < 8; q++){
        acc[q] *= invh;
        acc[q] += __shfl_xor(acc[q], 32);
        acc[q] = fmaxf(acc[q] + bias[c8 + q], 0.f);
        acc[q] += __shfl_xor(acc[q], 8);
        acc[q] += __shfl_xor(acc[q], 16);
        acc[q] *= 0.25f;
    }
    if (lane < 8){
        if (out_b){
            uint4 pb;
            pb.x = (unsigned)f2bf(acc[0]) | ((unsigned)f2bf(acc[1]) << 16);
            pb.y = (unsigned)f2bf(acc[2]) | ((unsigned)f2bf(acc[3]) << 16);
            pb.z = (unsigned)f2bf(acc[4]) | ((unsigned)f2bf(acc[5]) << 16);
            pb.w = (unsigned)f2bf(acc[6]) | ((unsigned)f2bf(acc[7]) << 16);
            *(uint4*)&out_b[(size_t)n * 64 + lane * 8] = pb;
        }
        if (out_f){
            *(float4*)&out_f[(size_t)n * 64 + lane * 8]     = make_float4(acc[0], acc[1], acc[2], acc[3]);
            *(float4*)&out_f[(size_t)n * 64 + lane * 8 + 4] = make_float4(acc[4], acc[5], acc[6], acc[7]);
        }
    }
}

// ---------------- final linear (BN scale/shift computed inline) --------------
__global__ __launch_bounds__(256) void mlp2(const float* __restrict__ z,
                                            const float* __restrict__ bn_sum,
                                            const float* __restrict__ bn_sumsq,
                                            const float* __restrict__ gamma,
                                            const float* __restrict__ beta,
                                            const float* __restrict__ Wm2,
                                            const float* __restrict__ bm2,
                                            float* __restrict__ out,
                                            int Nrows){
    __shared__ float s_scale[MLP_HID], s_shift[MLP_HID];
    const int tid = threadIdx.x;
    if (tid < MLP_HID){
        float inv = 1.f / (float)Nrows;
        float mu = bn_sum[tid] * inv;
        float var = bn_sumsq[tid] * inv - mu * mu;
        float rstd = rsqrtf(var + 1e-5f);
        float sc = rstd * gamma[tid];
        s_scale[tid] = sc;
        s_shift[tid] = beta[tid] - mu * sc;
    }
    __syncthreads();
    int n = (blockIdx.x * 256 + tid) >> 6;
    if (n >= Nrows) return;
    int lane = tid & 63;
    float a0 = 0.f, a1 = 0.f;
    for (int k = lane; k < MLP_HID; k += 64){
        float zn = z[(size_t)n * MLP_HID + k] * s_scale[k] + s_shift[k];
        a0 = fmaf(zn, Wm2[k * 2 + 0], a0);
        a1 = fmaf(zn, Wm2[k * 2 + 1], a1);
    }
    #pragma unroll
    for (int o = 32; o > 0; o >>= 1){
        a0 += __shfl_xor(a0, o);
        a1 += __shfl_xor(a1, o);
    }
    if (lane == 0){
        out[n * 2 + 0] = a0 + bm2[0];
        out[n * 2 + 1] = a1 + bm2[1];
    }
}

extern "C" void kernel_launch(void* const* d_in, const int* in_sizes, int n_in,
                              void* d_out, int out_size, void* d_ws, size_t ws_size,
                              hipStream_t stream) {
    const float* feat  = (const float*)d_in[0];
    const int*   src   = (const int*)  d_in[1];
    const int*   dst   = (const int*)  d_in[2];
    const float* W1    = (const float*)d_in[3];
    const float* al1   = (const float*)d_in[4];
    const float* ar1   = (const float*)d_in[5];
    const float* b1    = (const float*)d_in[6];
    const float* W2    = (const float*)d_in[7];
    const float* al2   = (const float*)d_in[8];
    const float* ar2   = (const float*)d_in[9];
    const float* b2    = (const float*)d_in[10];
    const float* Wm1   = (const float*)d_in[11];
    const float* bm1   = (const float*)d_in[12];
    const float* gamma = (const float*)d_in[13];
    const float* beta  = (const float*)d_in[14];
    const float* Wm2   = (const float*)d_in[15];
    const float* bm2   = (const float*)d_in[16];
    const int E = in_sizes[1];
    float* out = (float*)d_out;

    // ---- workspace layout ----
    unsigned short* h_bf   = (unsigned short*)d_ws;                 // N*256 bf16
    unsigned short* o1_bf  = h_bf   + (size_t)NNODES * 256;         // N*64 bf16
    unsigned short* W1T    = o1_bf  + (size_t)NNODES * 64;          // 256*128
    unsigned short* W2T    = W1T + 256 * 128;                       // 256*64
    float* z      = (float*)(W2T + 256 * 64);                       // N*200 f32
    float* out2_f = z      + (size_t)NNODES * MLP_HID;              // N*64 f32
    float* el     = out2_f + (size_t)NNODES * 64;                   // N*4
    float* er     = el     + (size_t)NNODES * 4;                    // N*4
    float* bn_sum   = er + (size_t)NNODES * 4;                      // 200
    float* bn_sumsq = bn_sum + MLP_HID;                             // 200
    int* cnt      = (int*)(bn_sumsq + MLP_HID);                     // N
    int* row_ptr  = cnt + NNODES;                                   // N+1
    int* cursor   = row_ptr + NNODES + 1;                           // N
    int* bsum     = cursor + NNODES;                                // 256
    int* boff     = bsum + 256;                                     // 256
    int* col_src  = boff + 256;                                     // E

    const dim3 blk(256);
    const int eg = (E + 255) / 256;
    const int gb = (NNODES + 63) / 64;
    const int ng4 = (NNODES + 3) / 4;       // wave-per-node edge grid

    // ---- init (weight transposes + zeroing) ----
    init_all<<<INIT_BLOCKS, blk, 0, stream>>>(W1, W1T, W2, W2T, cnt, bn_sum);

    // ---- CSR build ----
    csr_count<<<eg, blk, 0, stream>>>(dst, cnt, E);
    csr_bsum<<<NB_SCAN, blk, 0, stream>>>(cnt, bsum);
    csr_bscan<<<1, blk, 0, stream>>>(bsum, boff);
    csr_fill<<<NB_SCAN, blk, 0, stream>>>(cnt, boff, row_ptr, cursor);
    csr_scatter<<<eg, blk, 0, stream>>>(src, dst, cursor, col_src, E);

    // ---- layer 1 (f32 feat read directly, in-register bf16 pack) ----
    mfma_gemm_attn<128, true><<<gb, blk, 0, stream>>>(feat, W1T, al1, ar1,
                                                      h_bf, el, er, NNODES);
    gat_edge_v7<<<ng4, blk, 0, stream>>>(row_ptr, col_src, el, er, h_bf, b1,
                                         nullptr, o1_bf, NNODES);

    // ---- layer 2 (f32 output only; bf16 copy not needed downstream) ----
    mfma_gemm_attn<64, false><<<gb, blk, 0, stream>>>(o1_bf, W2T, al2, ar2,
                                                      h_bf, el, er, NNODES);
    gat_edge_v7<<<ng4, blk, 0, stream>>>(row_ptr, col_src, el, er, h_bf, b2,
                                         out2_f, nullptr, NNODES);

    // ---- MLP (f32, fused BN partials) ----
    gemm_tile<64,true,true><<<dim3((MLP_HID + 63) / 64, gb), blk, 0, stream>>>(
        out2_f, Wm1, bm1, z, bn_sum, bn_sumsq, NNODES, MLP_HID);

    mlp2<<<(NNODES * 64 + 255) / 256, blk, 0, stream>>>(
        z, bn_sum, bn_sumsq, gamma, beta, Wm2, bm2, out, NNODES);
}